// Round 6
// baseline (1751.958 us; speedup 1.0000x reference)
//
#include <hip/hip_runtime.h>

#define NN 4096
#define NSTEPS 100
#define TPB 512
#define NBLK 256     // 1 block per CU; 16 rows per block, K pinned in VGPRs

typedef float v2f __attribute__((ext_vector_type(2)));

// Coherent (cross-XCD) 8-byte load/store: relaxed agent-scope atomics compile
// to sc-flagged global ops that bypass the non-coherent L1/L2 and hit the
// coherence point directly — no release/acquire cache-maintenance.
__device__ __forceinline__ void zstore_u64(float2* p, unsigned long long u) {
    __hip_atomic_store((unsigned long long*)p, u, __ATOMIC_RELAXED,
                       __HIP_MEMORY_SCOPE_AGENT);
}
__device__ __forceinline__ unsigned long long zload_u64(const float2* p) {
    return __hip_atomic_load((const unsigned long long*)p, __ATOMIC_RELAXED,
                             __HIP_MEMORY_SCOPE_AGENT);
}

// R7 = R5 geometry (R6's 2-blocks/CU occupancy bet regressed 2.6x: doubled
// poll population + doubled fixed per-thread overhead + co-resident blocks
// stall on the SAME global wavefront, no mutual hiding). Two changes vs R5:
//  1. kA pin HOISTED out of the step loop. R5 pinned all 128 kA floats into
//     arch VGPRs every iteration ("+v" asm inside the loop) while the
//     allocator only gave 108 arch VGPRs -> AGPR<->VGPR shuttle (~256
//     v_accvgpr moves/step/thread, comparable to the dot's 256 FMAs; the
//     reason measured VALU issue was 2.5x the hand-counted math). One asm
//     pin after the load keeps the values opaque (no global-load refold)
//     without forcing per-step residency.
//  2. Packed dot: acc[r] += kA[r][j] * (zre,zim) as ext_vector float2 —
//     the scalar-k-times-complex-z shape maps to v_pk_fma_f32 (halves dot
//     issue if taken; harmless if not).
// Everything else (early-issue polls, 37-shuffle butterfly, per-wave ODE,
// parity-double-buffered P, tag protocol) is byte-identical to R5.
__global__ __launch_bounds__(TPB, 2) void k_persist(
    const float* __restrict__ K, const float2* __restrict__ z0,
    float2* __restrict__ zb0, float2* __restrict__ zb1,
    float2* __restrict__ zfinal, const float* __restrict__ omega_p,
    const float* __restrict__ dt_p) {
    __shared__ float P[2][8][68];   // 68: +4 pad so q-stride hits new banks

    const int tid  = threadIdx.x;
    const int bid  = blockIdx.x;
    const int w    = tid >> 6, lane = tid & 63;   // w = column-eighth
    const int colbase = w * 512 + lane;           // col_j = colbase + j*64

    const float omega = *omega_p;
    const float dt    = *dt_p;
    const float inv2n = 1.0f / (2.0f * NN);

    // ---- K fragment: 16 rows x 8 strided cols = 128 scalars ----
    float kA[16][8];
#pragma unroll
    for (int r = 0; r < 16; ++r) {
        const float* Kr = K + (size_t)(bid * 16 + r) * NN + colbase;
#pragma unroll
        for (int j = 0; j < 8; ++j) kA[r][j] = Kr[j * 64];
    }
    // One-time opacity pin: values can never be refolded into global loads,
    // but the allocator is free to give them a stable home (VGPR or AGPR)
    // for the whole loop — no per-step forced relocation.
#pragma unroll
    for (int r = 0; r < 16; ++r)
#pragma unroll
        for (int j = 0; j < 8; ++j) asm volatile("" : "+v"(kA[r][j]));

    // ---- persistent ODE state: wave w's lanes 0/32 hold rows 2w, 2w+1 ----
    float x = 0.f, y = 0.f;
    if ((lane & 31) == 0) {
        float2 zc = z0[bid * 16 + 2 * w + (lane >> 5)];
        x = zc.x; y = zc.y;
    }

    unsigned long long v[8];   // in-flight tagged loads for the NEXT step

    for (int s = 0; s < NSTEPS; ++s) {
        // ---- gather this thread's 8 z elements into registers ----
        v2f zv[8];
        if (s == 0) {
#pragma unroll
            for (int j = 0; j < 8; ++j) {
                float2 zc = z0[colbase + j * 64];
                zv[j].x = zc.x; zv[j].y = zc.y;
            }
        } else {
            // v[] was issued at the end of step s-1; finish the poll.
            const float2* zsrc = (s & 1) ? zb1 : zb0;
            const unsigned tag = (unsigned)(s & 7);
            unsigned stale = 0u;
#pragma unroll
            for (int j = 0; j < 8; ++j)
                stale |= (((unsigned)v[j] & 7u) != tag) ? (1u << j) : 0u;
            while (stale) {                      // batched re-poll
                __builtin_amdgcn_s_sleep(1);
#pragma unroll
                for (int j = 0; j < 8; ++j)
                    if (stale & (1u << j))
                        v[j] = zload_u64(zsrc + colbase + j * 64);
#pragma unroll
                for (int j = 0; j < 8; ++j)
                    if ((stale & (1u << j)) && ((unsigned)v[j] & 7u) == tag)
                        stale &= ~(1u << j);
            }
#pragma unroll
            for (int j = 0; j < 8; ++j) {
                union { unsigned u; float f; } cx, cy;
                cx.u = (unsigned)v[j];
                cy.u = (unsigned)(v[j] >> 32);
                zv[j].x = cx.f; zv[j].y = cy.f;
            }
        }

        // ---- dots: 16 rows x 8 cols per thread, packed Re/Im ----
        v2f acc[16];
#pragma unroll
        for (int r = 0; r < 16; ++r) acc[r] = (v2f)(0.f);
#pragma unroll
        for (int j = 0; j < 8; ++j) {
#pragma unroll
            for (int r = 0; r < 16; ++r) acc[r] += kA[r][j] * zv[j];
        }

        // ---- EARLY-ISSUE the next step's tagged loads (fly during
        //      butterfly + barrier + ODE; checked at next loop top) ----
        if (s + 1 < NSTEPS) {
            const float2* zn = ((s + 1) & 1) ? zb1 : zb0;
#pragma unroll
            for (int j = 0; j < 8; ++j)
                v[j] = zload_u64(zn + colbase + j * 64);
        }

        // ---- distribute-and-halve butterfly: 31 shuffles/thread ----
        // acc index i: i<16 -> Re(row i); i>=16 -> Im(row i-16).
        float a32[32];
#pragma unroll
        for (int r = 0; r < 16; ++r) { a32[r] = acc[r].x; a32[16 + r] = acc[r].y; }
        float b16[16];
#pragma unroll
        for (int m = 0; m < 16; ++m) {
            float aa = a32[2 * m], bb = a32[2 * m + 1];
            bool hi = lane & 1;
            float snd = hi ? aa : bb, kp = hi ? bb : aa;
            b16[m] = kp + __shfl_xor(snd, 1, 64);
        }
        float b8[8];
#pragma unroll
        for (int m = 0; m < 8; ++m) {
            float aa = b16[2 * m], bb = b16[2 * m + 1];
            bool hi = lane & 2;
            float snd = hi ? aa : bb, kp = hi ? bb : aa;
            b8[m] = kp + __shfl_xor(snd, 2, 64);
        }
        float b4[4];
#pragma unroll
        for (int m = 0; m < 4; ++m) {
            float aa = b8[2 * m], bb = b8[2 * m + 1];
            bool hi = lane & 4;
            float snd = hi ? aa : bb, kp = hi ? bb : aa;
            b4[m] = kp + __shfl_xor(snd, 4, 64);
        }
        float b2[2];
#pragma unroll
        for (int m = 0; m < 2; ++m) {
            float aa = b4[2 * m], bb = b4[2 * m + 1];
            bool hi = lane & 8;
            float snd = hi ? aa : bb, kp = hi ? bb : aa;
            b2[m] = kp + __shfl_xor(snd, 8, 64);
        }
        {
            float aa = b2[0], bb = b2[1];
            bool hi = lane & 16;
            float snd = hi ? aa : bb, kp = hi ? bb : aa;
            float red = kp + __shfl_xor(snd, 16, 64);
            // lane l holds acc index (l&31), summed over its 32-lane half
            P[s & 1][w][lane] = red;
        }
        __syncthreads();

        // ---- per-wave ODE: wave w owns rows 2w, 2w+1 ----
        {
            const int par = s & 1;
            const int r0 = 2 * w, r1 = 2 * w + 1;
            int q    = lane & 7;
            int half = (lane >> 3) & 1;
            int sel  = lane >> 4;                       // 0..3
            int rr   = (sel & 2) ? r1 : r0;
            int idx  = ((sel & 1) << 4) + rr;           // +16 selects Im
            float val = P[par][q][half * 32 + idx];
            val += __shfl_xor(val, 1, 64);              // sum over q
            val += __shfl_xor(val, 2, 64);
            val += __shfl_xor(val, 4, 64);
            val += __shfl_xor(val, 8, 64);              // sum the two halves
            float other = __shfl_xor(val, 16, 64);      // Im to lanes 0/32
            if ((lane & 31) == 0) {                     // lanes 0 and 32
                float u  = val;                         // Re(K z) row
                float vv = other;                       // Im(K z) row
                float A = x * x - y * y;                // Re(z^2)
                float B = 2.0f * x * y;                 // Im(z^2)
                float dzr = inv2n * (u  - (u * A + vv * B)) + omega * x;
                float dzi = inv2n * (vv - (u * B - vv * A)) + omega * y;
                float nx = x + dt * dzr;
                float ny = y + dt * dzi;
                float a2 = nx * nx + ny * ny;
                if (a2 >= 0.999f * 0.999f) {
                    float sc = 0.999f / sqrtf(a2);
                    nx *= sc; ny *= sc;
                }
                x = nx; y = ny;                         // state stays in regs
                int gr = bid * 16 + r0 + (lane >> 5);
                if (s == NSTEPS - 1) {
                    zfinal[gr] = make_float2(nx, ny);   // plain, untagged
                } else {
                    union { float f; unsigned u; } cx, cy;
                    cx.f = nx; cy.f = ny;
                    cx.u = (cx.u & ~7u) | (unsigned)((s + 1) & 7);
                    unsigned long long pk =
                        (unsigned long long)cx.u |
                        ((unsigned long long)cy.u << 32);
                    float2* zo = ((s + 1) & 1) ? zb1 : zb0;
                    zstore_u64(zo + gr, pk);            // fire-and-forget
                }
            }
        }
        // no trailing barrier — P is parity-double-buffered and the tag
        // protocol transitively orders (s+2)-writes after (s)-reads
    }
}

// ---- generic fallback: per-step launches ----
__global__ __launch_bounds__(256) void k_step_f32(
    const float* __restrict__ K, const float2* __restrict__ zin,
    float2* __restrict__ zout, const float* __restrict__ omega_p,
    const float* __restrict__ dt_p, int n) {
    const int wave = threadIdx.x >> 6;
    const int lane = threadIdx.x & 63;
    const int row  = blockIdx.x * 4 + wave;
    if (row >= n) return;
    float sr = 0.0f, si = 0.0f;
    for (int c = lane; c < n; c += 64) {
        float k = K[(size_t)row * n + c];
        float2 z = zin[c];
        sr += k * z.x;
        si += k * z.y;
    }
#pragma unroll
    for (int off = 32; off; off >>= 1) {
        sr += __shfl_down(sr, off, 64);
        si += __shfl_down(si, off, 64);
    }
    if (lane == 0) {
        float u = sr, v = si;
        float2 zc = zin[row];
        float x = zc.x, y = zc.y;
        float inv2n = 1.0f / (2.0f * n);
        float A = x * x - y * y, B = 2.0f * x * y;
        float dzr = inv2n * (u - (u * A + v * B)) + (*omega_p) * x;
        float dzi = inv2n * (v - (u * B - v * A)) + (*omega_p) * y;
        float nx = x + (*dt_p) * dzr, ny = y + (*dt_p) * dzi;
        float a2 = nx * nx + ny * ny;
        if (a2 >= 0.999f * 0.999f) { float sc = 0.999f / sqrtf(a2); nx *= sc; ny *= sc; }
        zout[row] = make_float2(nx, ny);
    }
}

extern "C" void kernel_launch(void* const* d_in, const int* in_sizes, int n_in,
                              void* d_out, int out_size, void* d_ws, size_t ws_size,
                              hipStream_t stream) {
    const float2* z0      = (const float2*)d_in[0];
    const float*  K       = (const float*)d_in[1];
    const float*  omega_p = (const float*)d_in[2];
    const float*  dt_p    = (const float*)d_in[3];
    const int n = in_sizes[0] / 2;
    float2* out = (float2*)d_out;

    const size_t need = 2 * (size_t)NN * sizeof(float2);   // two z buffers
    if (n == NN && ws_size >= need) {
        float2* zb0 = (float2*)d_ws;
        float2* zb1 = zb0 + NN;
        hipMemsetAsync(d_ws, 0, need, stream);   // tag 0 != any live tag (1,2)
        k_persist<<<NBLK, TPB, 0, stream>>>(K, z0, zb0, zb1, out,
                                            omega_p, dt_p);
    } else {
        float2* zb0 = (float2*)d_ws;
        float2* zb1 = zb0 + n;
        const float2* cur = z0;
        for (int s = 0; s < NSTEPS; ++s) {
            float2* nxt = (s == NSTEPS - 1) ? out : ((s & 1) ? zb1 : zb0);
            k_step_f32<<<(n + 3) / 4, 256, 0, stream>>>(K, cur, nxt, omega_p, dt_p, n);
            cur = nxt;
        }
    }
}

// Round 7
// 527.058 us; speedup vs baseline: 3.3240x; 3.3240x over previous
//
#include <hip/hip_runtime.h>

#define NN 4096
#define NSTEPS 100
#define TPB 512
#define NBLK 256     // 1 block per CU; 16 rows per block, K pinned in AGPRs

typedef float v2f __attribute__((ext_vector_type(2)));

// Coherent (cross-XCD) 8-byte load/store: relaxed agent-scope atomics compile
// to sc-flagged global ops that bypass the non-coherent L1/L2 and hit the
// coherence point directly — no release/acquire cache-maintenance.
__device__ __forceinline__ void zstore_u64(float2* p, unsigned long long u) {
    __hip_atomic_store((unsigned long long*)p, u, __ATOMIC_RELAXED,
                       __HIP_MEMORY_SCOPE_AGENT);
}
__device__ __forceinline__ unsigned long long zload_u64(const float2* p) {
    return __hip_atomic_load((const unsigned long long*)p, __ATOMIC_RELAXED,
                             __HIP_MEMORY_SCOPE_AGENT);
}

// R8 = R5 structure with kA homed in AGPRs.
// History: R5 pinned kA with "+v" per iteration -> allocator had only 108
// arch VGPRs for 128 live values -> AGPR<->VGPR shuttle every step (~half of
// VALU issue). R7 hoisted the pin -> allocator spilled kA to SCRATCH, reloaded
// 22MB/step from HBM (FETCH 46MB -> 2.2GB, 5x regression).
// Fix: per-iteration pin with the "a" (AGPR) constraint. gfx950 has a unified
// VGPR/AGPR file and VALU reads AGPR sources directly, so:
//   - the pin is satisfied with ZERO moves (values permanently live in AGPRs),
//   - remat/spill of kA is illegal (asm redefines it every iteration),
//   - arch-VGPR pressure drops to ~80 (zv/acc/butterfly) -> no spill,
//   - dot reads kA straight from AGPRs (worst case: 1 accvgpr_read per use,
//     still < R5's shuttle).
// Packed v2f dot kept: acc[r] += kA[r][j] * (zre,zim) -> v_pk_fma_f32 halves
// dot issue vs scalar.
// Everything else (early-issue polls, butterfly, per-wave ODE, parity-
// double-buffered P, tag protocol) is byte-identical to R5.
__global__ __launch_bounds__(TPB, 2) void k_persist(
    const float* __restrict__ K, const float2* __restrict__ z0,
    float2* __restrict__ zb0, float2* __restrict__ zb1,
    float2* __restrict__ zfinal, const float* __restrict__ omega_p,
    const float* __restrict__ dt_p) {
    __shared__ float P[2][8][68];   // 68: +4 pad so q-stride hits new banks

    const int tid  = threadIdx.x;
    const int bid  = blockIdx.x;
    const int w    = tid >> 6, lane = tid & 63;   // w = column-eighth
    const int colbase = w * 512 + lane;           // col_j = colbase + j*64

    const float omega = *omega_p;
    const float dt    = *dt_p;
    const float inv2n = 1.0f / (2.0f * NN);

    // ---- K fragment: 16 rows x 8 strided cols = 128 scalars in AGPRs ----
    float kA[16][8];
#pragma unroll
    for (int r = 0; r < 16; ++r) {
        const float* Kr = K + (size_t)(bid * 16 + r) * NN + colbase;
#pragma unroll
        for (int j = 0; j < 8; ++j) kA[r][j] = Kr[j * 64];
    }

    // ---- persistent ODE state: wave w's lanes 0/32 hold rows 2w, 2w+1 ----
    float x = 0.f, y = 0.f;
    if ((lane & 31) == 0) {
        float2 zc = z0[bid * 16 + 2 * w + (lane >> 5)];
        x = zc.x; y = zc.y;
    }

    unsigned long long v[8];   // in-flight tagged loads for the NEXT step

    for (int s = 0; s < NSTEPS; ++s) {
        // Pin kA into AGPRs: opaque redefinition each iteration (no remat,
        // no scratch spill legal) — zero-cost since AGPR is the stable home.
#pragma unroll
        for (int r = 0; r < 16; ++r)
#pragma unroll
            for (int j = 0; j < 8; ++j) asm volatile("" : "+a"(kA[r][j]));

        // ---- gather this thread's 8 z elements into registers ----
        v2f zv[8];
        if (s == 0) {
#pragma unroll
            for (int j = 0; j < 8; ++j) {
                float2 zc = z0[colbase + j * 64];
                zv[j].x = zc.x; zv[j].y = zc.y;
            }
        } else {
            // v[] was issued at the end of step s-1; finish the poll.
            const float2* zsrc = (s & 1) ? zb1 : zb0;
            const unsigned tag = (unsigned)(s & 7);
            unsigned stale = 0u;
#pragma unroll
            for (int j = 0; j < 8; ++j)
                stale |= (((unsigned)v[j] & 7u) != tag) ? (1u << j) : 0u;
            while (stale) {                      // batched re-poll
                __builtin_amdgcn_s_sleep(1);
#pragma unroll
                for (int j = 0; j < 8; ++j)
                    if (stale & (1u << j))
                        v[j] = zload_u64(zsrc + colbase + j * 64);
#pragma unroll
                for (int j = 0; j < 8; ++j)
                    if ((stale & (1u << j)) && ((unsigned)v[j] & 7u) == tag)
                        stale &= ~(1u << j);
            }
#pragma unroll
            for (int j = 0; j < 8; ++j) {
                union { unsigned u; float f; } cx, cy;
                cx.u = (unsigned)v[j];
                cy.u = (unsigned)(v[j] >> 32);
                zv[j].x = cx.f; zv[j].y = cy.f;
            }
        }

        // ---- dots: 16 rows x 8 cols per thread, packed Re/Im ----
        v2f acc[16];
#pragma unroll
        for (int r = 0; r < 16; ++r) acc[r] = (v2f)(0.f);
#pragma unroll
        for (int j = 0; j < 8; ++j) {
#pragma unroll
            for (int r = 0; r < 16; ++r) acc[r] += kA[r][j] * zv[j];
        }

        // ---- EARLY-ISSUE the next step's tagged loads (fly during
        //      butterfly + barrier + ODE; checked at next loop top) ----
        if (s + 1 < NSTEPS) {
            const float2* zn = ((s + 1) & 1) ? zb1 : zb0;
#pragma unroll
            for (int j = 0; j < 8; ++j)
                v[j] = zload_u64(zn + colbase + j * 64);
        }

        // ---- distribute-and-halve butterfly: 31 shuffles/thread ----
        // acc index i: i<16 -> Re(row i); i>=16 -> Im(row i-16).
        float a32[32];
#pragma unroll
        for (int r = 0; r < 16; ++r) { a32[r] = acc[r].x; a32[16 + r] = acc[r].y; }
        float b16[16];
#pragma unroll
        for (int m = 0; m < 16; ++m) {
            float aa = a32[2 * m], bb = a32[2 * m + 1];
            bool hi = lane & 1;
            float snd = hi ? aa : bb, kp = hi ? bb : aa;
            b16[m] = kp + __shfl_xor(snd, 1, 64);
        }
        float b8[8];
#pragma unroll
        for (int m = 0; m < 8; ++m) {
            float aa = b16[2 * m], bb = b16[2 * m + 1];
            bool hi = lane & 2;
            float snd = hi ? aa : bb, kp = hi ? bb : aa;
            b8[m] = kp + __shfl_xor(snd, 2, 64);
        }
        float b4[4];
#pragma unroll
        for (int m = 0; m < 4; ++m) {
            float aa = b8[2 * m], bb = b8[2 * m + 1];
            bool hi = lane & 4;
            float snd = hi ? aa : bb, kp = hi ? bb : aa;
            b4[m] = kp + __shfl_xor(snd, 4, 64);
        }
        float b2[2];
#pragma unroll
        for (int m = 0; m < 2; ++m) {
            float aa = b4[2 * m], bb = b4[2 * m + 1];
            bool hi = lane & 8;
            float snd = hi ? aa : bb, kp = hi ? bb : aa;
            b2[m] = kp + __shfl_xor(snd, 8, 64);
        }
        {
            float aa = b2[0], bb = b2[1];
            bool hi = lane & 16;
            float snd = hi ? aa : bb, kp = hi ? bb : aa;
            float red = kp + __shfl_xor(snd, 16, 64);
            // lane l holds acc index (l&31), summed over its 32-lane half
            P[s & 1][w][lane] = red;
        }
        __syncthreads();

        // ---- per-wave ODE: wave w owns rows 2w, 2w+1 ----
        {
            const int par = s & 1;
            const int r0 = 2 * w, r1 = 2 * w + 1;
            int q    = lane & 7;
            int half = (lane >> 3) & 1;
            int sel  = lane >> 4;                       // 0..3
            int rr   = (sel & 2) ? r1 : r0;
            int idx  = ((sel & 1) << 4) + rr;           // +16 selects Im
            float val = P[par][q][half * 32 + idx];
            val += __shfl_xor(val, 1, 64);              // sum over q
            val += __shfl_xor(val, 2, 64);
            val += __shfl_xor(val, 4, 64);
            val += __shfl_xor(val, 8, 64);              // sum the two halves
            float other = __shfl_xor(val, 16, 64);      // Im to lanes 0/32
            if ((lane & 31) == 0) {                     // lanes 0 and 32
                float u  = val;                         // Re(K z) row
                float vv = other;                       // Im(K z) row
                float A = x * x - y * y;                // Re(z^2)
                float B = 2.0f * x * y;                 // Im(z^2)
                float dzr = inv2n * (u  - (u * A + vv * B)) + omega * x;
                float dzi = inv2n * (vv - (u * B - vv * A)) + omega * y;
                float nx = x + dt * dzr;
                float ny = y + dt * dzi;
                float a2 = nx * nx + ny * ny;
                if (a2 >= 0.999f * 0.999f) {
                    float sc = 0.999f / sqrtf(a2);
                    nx *= sc; ny *= sc;
                }
                x = nx; y = ny;                         // state stays in regs
                int gr = bid * 16 + r0 + (lane >> 5);
                if (s == NSTEPS - 1) {
                    zfinal[gr] = make_float2(nx, ny);   // plain, untagged
                } else {
                    union { float f; unsigned u; } cx, cy;
                    cx.f = nx; cy.f = ny;
                    cx.u = (cx.u & ~7u) | (unsigned)((s + 1) & 7);
                    unsigned long long pk =
                        (unsigned long long)cx.u |
                        ((unsigned long long)cy.u << 32);
                    float2* zo = ((s + 1) & 1) ? zb1 : zb0;
                    zstore_u64(zo + gr, pk);            // fire-and-forget
                }
            }
        }
        // no trailing barrier — P is parity-double-buffered and the tag
        // protocol transitively orders (s+2)-writes after (s)-reads
    }
}

// ---- generic fallback: per-step launches ----
__global__ __launch_bounds__(256) void k_step_f32(
    const float* __restrict__ K, const float2* __restrict__ zin,
    float2* __restrict__ zout, const float* __restrict__ omega_p,
    const float* __restrict__ dt_p, int n) {
    const int wave = threadIdx.x >> 6;
    const int lane = threadIdx.x & 63;
    const int row  = blockIdx.x * 4 + wave;
    if (row >= n) return;
    float sr = 0.0f, si = 0.0f;
    for (int c = lane; c < n; c += 64) {
        float k = K[(size_t)row * n + c];
        float2 z = zin[c];
        sr += k * z.x;
        si += k * z.y;
    }
#pragma unroll
    for (int off = 32; off; off >>= 1) {
        sr += __shfl_down(sr, off, 64);
        si += __shfl_down(si, off, 64);
    }
    if (lane == 0) {
        float u = sr, v = si;
        float2 zc = zin[row];
        float x = zc.x, y = zc.y;
        float inv2n = 1.0f / (2.0f * n);
        float A = x * x - y * y, B = 2.0f * x * y;
        float dzr = inv2n * (u - (u * A + v * B)) + (*omega_p) * x;
        float dzi = inv2n * (v - (u * B - v * A)) + (*omega_p) * y;
        float nx = x + (*dt_p) * dzr, ny = y + (*dt_p) * dzi;
        float a2 = nx * nx + ny * ny;
        if (a2 >= 0.999f * 0.999f) { float sc = 0.999f / sqrtf(a2); nx *= sc; ny *= sc; }
        zout[row] = make_float2(nx, ny);
    }
}

extern "C" void kernel_launch(void* const* d_in, const int* in_sizes, int n_in,
                              void* d_out, int out_size, void* d_ws, size_t ws_size,
                              hipStream_t stream) {
    const float2* z0      = (const float2*)d_in[0];
    const float*  K       = (const float*)d_in[1];
    const float*  omega_p = (const float*)d_in[2];
    const float*  dt_p    = (const float*)d_in[3];
    const int n = in_sizes[0] / 2;
    float2* out = (float2*)d_out;

    const size_t need = 2 * (size_t)NN * sizeof(float2);   // two z buffers
    if (n == NN && ws_size >= need) {
        float2* zb0 = (float2*)d_ws;
        float2* zb1 = zb0 + NN;
        hipMemsetAsync(d_ws, 0, need, stream);   // tag 0 != any live tag (1,2)
        k_persist<<<NBLK, TPB, 0, stream>>>(K, z0, zb0, zb1, out,
                                            omega_p, dt_p);
    } else {
        float2* zb0 = (float2*)d_ws;
        float2* zb1 = zb0 + n;
        const float2* cur = z0;
        for (int s = 0; s < NSTEPS; ++s) {
            float2* nxt = (s == NSTEPS - 1) ? out : ((s & 1) ? zb1 : zb0);
            k_step_f32<<<(n + 3) / 4, 256, 0, stream>>>(K, cur, nxt, omega_p, dt_p, n);
            cur = nxt;
        }
    }
}